// Round 14
// baseline (346.498 us; speedup 1.0000x reference)
//
#include <hip/hip_runtime.h>
#include <hip/hip_bf16.h>

typedef __bf16 bf16_t;
typedef __attribute__((ext_vector_type(8))) __bf16 bf16x8;
typedef __attribute__((ext_vector_type(4))) __bf16 bf16x4;
typedef __attribute__((ext_vector_type(4))) float f32x4;

#define MFMA16(a, b, c) __builtin_amdgcn_mfma_f32_16x16x32_bf16((a), (b), (c), 0, 0, 0)

__device__ __forceinline__ void gload_lds16(const void* g, void* l) {
    __builtin_amdgcn_global_load_lds(
        (const __attribute__((address_space(1))) void*)g,
        (__attribute__((address_space(3))) void*)l, 16, 0, 0);
}

// ---------------------------------------------------------------------------
// Kernel 1: QKV projection (unchanged). Q pre-scaled by (1/sqrt(128))*log2e;
// V written transposed as [b][h][t].
// ---------------------------------------------------------------------------
__global__ __launch_bounds__(256, 3) void proj_qkv(
    const float* __restrict__ X,
    const float* __restrict__ W0, const float* __restrict__ W1, const float* __restrict__ W2,
    bf16_t* __restrict__ O0, bf16_t* __restrict__ O1, bf16_t* __restrict__ O2)
{
    __shared__ __align__(16) char As[128 * 128];
    __shared__ __align__(16) char Bs[128 * 128];

    const int tid = threadIdx.x;
    const int wid = tid >> 6;
    const int lane = tid & 63;
    const int l15 = lane & 15, l4 = lane >> 4;
    const int wr = wid >> 1, wc = wid & 1;
    const int m0 = blockIdx.x * 128;

    const float* W = (blockIdx.y == 0) ? W0 : (blockIdx.y == 1 ? W1 : W2);

    const int r0 = tid >> 4;
    const int kq = tid & 15;
    const int swz = ((r0 & 7) << 4);

    f32x4 acc[4][4] = {};
    float4 xr[8];

    #pragma unroll
    for (int i = 0; i < 8; ++i)
        xr[i] = *(const float4*)(X + (size_t)(m0 + r0 + i * 16) * 1024 + kq * 4);

    for (int ks = 0; ks < 16; ++ks) {
        const int kb = ks * 64;
        #pragma unroll
        for (int i = 0; i < 8; ++i) {
            const int r = r0 + i * 16;
            bf16x4 av; av[0] = (bf16_t)xr[i].x; av[1] = (bf16_t)xr[i].y;
            av[2] = (bf16_t)xr[i].z; av[3] = (bf16_t)xr[i].w;
            *(bf16x4*)(As + r * 128 + ((kq * 8) ^ swz)) = av;
        }
        #pragma unroll
        for (int i = 0; i < 8; ++i) {
            const int r = r0 + i * 16;
            float4 wa = *(const float4*)(W + (size_t)r * 1024 + kb + kq * 4);
            bf16x4 wv; wv[0] = (bf16_t)wa.x; wv[1] = (bf16_t)wa.y;
            wv[2] = (bf16_t)wa.z; wv[3] = (bf16_t)wa.w;
            *(bf16x4*)(Bs + r * 128 + ((kq * 8) ^ swz)) = wv;
        }
        __syncthreads();
        if (ks < 15) {
            #pragma unroll
            for (int i = 0; i < 8; ++i)
                xr[i] = *(const float4*)(X + (size_t)(m0 + r0 + i * 16) * 1024 + kb + 64 + kq * 4);
        }
        #pragma unroll
        for (int kk = 0; kk < 64; kk += 32) {
            const int kbyte = 2 * kk + 16 * l4;
            bf16x8 af[4], bfr[4];
            #pragma unroll
            for (int mi = 0; mi < 4; ++mi) {
                int r = wr * 64 + mi * 16 + l15;
                af[mi] = *(const bf16x8*)(As + r * 128 + (kbyte ^ ((r & 7) << 4)));
            }
            #pragma unroll
            for (int ni = 0; ni < 4; ++ni) {
                int r = wc * 64 + ni * 16 + l15;
                bfr[ni] = *(const bf16x8*)(Bs + r * 128 + (kbyte ^ ((r & 7) << 4)));
            }
            #pragma unroll
            for (int mi = 0; mi < 4; ++mi)
                #pragma unroll
                for (int ni = 0; ni < 4; ++ni)
                    acc[mi][ni] = MFMA16(af[mi], bfr[ni], acc[mi][ni]);
        }
        __syncthreads();
    }

    if (blockIdx.y < 2) {
        const float sc = (blockIdx.y == 0) ? 0.12751754816f : 1.0f;  // 1/sqrt(128)*log2e
        bf16_t* O = (blockIdx.y == 0) ? O0 : O1;
        #pragma unroll
        for (int mi = 0; mi < 4; ++mi)
            #pragma unroll
            for (int ni = 0; ni < 4; ++ni) {
                int row = m0 + wr * 64 + mi * 16 + l4 * 4;
                int col = wc * 64 + ni * 16 + l15;
                #pragma unroll
                for (int r = 0; r < 4; ++r)
                    O[(size_t)(row + r) * 128 + col] = (bf16_t)(acc[mi][ni][r] * sc);
            }
    } else {
        #pragma unroll
        for (int mi = 0; mi < 4; ++mi)
            #pragma unroll
            for (int ni = 0; ni < 4; ++ni) {
                int row0 = m0 + wr * 64 + mi * 16 + l4 * 4;
                int col = wc * 64 + ni * 16 + l15;
                int bb = row0 >> 12, t0 = row0 & 4095;
                bf16x4 pk;
                #pragma unroll
                for (int r = 0; r < 4; ++r) pk[r] = (bf16_t)acc[mi][ni][r];
                *(bf16x4*)(O2 + ((size_t)bb << 19) + (size_t)col * 4096 + t0) = pk;
            }
    }
}

// ---------------------------------------------------------------------------
// Kernel 2: causal flash attention — 8-wave blocks for 4 waves/SIMD TLP.
// 512 blocks x 512 threads. Block processes atoms p=j then 127-j; waves
// kv-split mod 8 (pair-sum work constant +-1 tile). Per-tile pipeline is
// r11's proven chain: K->regs prefetch, V via global_load_lds (single 8KB
// buffer/wave, WAR-guarded by lgkmcnt(0)), counted vmcnt(8), P via swizzled
// per-wave LDS, base-2 deferred-max softmax, ones-MFMA denominator.
// LDS 80KB -> 2 blocks/CU; VGPR capped 128 (launch_bounds 512,4) -> 16 w/CU.
// ---------------------------------------------------------------------------
__global__ __launch_bounds__(512, 4) void attn_fwd(
    const bf16_t* __restrict__ Qb, const bf16_t* __restrict__ Kb,
    const bf16_t* __restrict__ Vtg, float* __restrict__ out, int Bn)
{
    // [0,65536): per-wave V buffer (8KB x 8, [128h][64B kv-row], swizzled);
    //            merge reuses as 8 x 8KB O-dump per qs-pass.
    // [65536,81920): per-wave P (2KB x 8); merge stats overlay (P dead).
    __shared__ __align__(16) char lds[81920];

    const int tid = threadIdx.x, wid = tid >> 6, lane = tid & 63;
    const int l15 = lane & 15, l4 = lane >> 4;

    const int blk = blockIdx.x;
    const int b = blk % Bn;              // batch == XCD -> K/V L2-resident
    const int j = blk / Bn;              // 0..63

    const size_t base = (size_t)b * 4096 * 128;
    const size_t baseVT = (size_t)b << 19;

    char* Vw = lds + wid * 8192;
    char* Pw = lds + 65536 + wid * 2048;
    const int pswz = (l15 >> 1) & 3;     // P 16B-chunk XOR key
    const int vswz = (l15 >> 1) & 3;     // V 16B-chunk XOR key (read side)

    const int sh = lane >> 2;            // staging: row within 16-row chunk
    const int skb = (((lane & 3) ^ ((sh >> 1) & 3))) * 8;  // V src pre-swizzle

    // Constant all-ones A fragment: row-sum MFMA for the softmax denominator.
    bf16x8 aones;
    #pragma unroll
    for (int e = 0; e < 8; ++e) aones[e] = (bf16_t)1.0f;

    for (int seg = 0; seg < 2; ++seg) {
        const int p = seg ? (127 - j) : j;     // 32q atom index
        const int q0 = p << 5;
        const int nt = (p >= wid) ? ((p - wid) >> 3) + 1 : 0;  // my tiles: lt = wid+8i

        // Q fragments (B-operand): col q = q0+16qs+l15, k = 32kf+8l4+e.
        bf16x8 aq[2][4];
        #pragma unroll
        for (int qs = 0; qs < 2; ++qs)
            #pragma unroll
            for (int kf = 0; kf < 4; ++kf)
                aq[qs][kf] = *(const bf16x8*)(Qb + base
                    + (size_t)(q0 + 16 * qs + l15) * 128 + 32 * kf + 8 * l4);

        float mx[2] = {-1e30f, -1e30f};
        f32x4 ls_acc[2] = {};              // denominator accumulator (ones-MFMA)
        f32x4 o[2][8] = {};
        bf16x8 kreg[2][4];

        auto stageV = [&](int i) {
            const int kv0 = (wid + 8 * i) << 5;
            #pragma unroll
            for (int c = 0; c < 8; ++c) {
                const bf16_t* src = Vtg + baseVT + (size_t)(16 * c + sh) * 4096 + kv0 + skb;
                gload_lds16(src, Vw + c * 1024);
            }
        };
        auto loadK = [&](int i) {
            const int kv0 = (wid + 8 * i) << 5;
            const bf16_t* kp = Kb + base + (size_t)(kv0 + l15) * 128 + 8 * l4;
            #pragma unroll
            for (int ni = 0; ni < 2; ++ni)
                #pragma unroll
                for (int kf = 0; kf < 4; ++kf)
                    kreg[ni][kf] = *(const bf16x8*)(kp + (size_t)ni * 2048 + kf * 32);
        };

        if (nt > 0) { loadK(0); stageV(0); }

        for (int i = 0; i < nt; ++i) {
            const int lt = wid + 8 * i;
            const int kv0 = lt << 5;

            // S^T = K * Q^T : D row = kv (16ni+4l4+r), col = q (l15).
            f32x4 sa[2][2];
            #pragma unroll
            for (int qs = 0; qs < 2; ++qs)
                #pragma unroll
                for (int ni = 0; ni < 2; ++ni) sa[qs][ni] = (f32x4){0.f, 0.f, 0.f, 0.f};
            __builtin_amdgcn_s_setprio(1);
            #pragma unroll
            for (int kf = 0; kf < 4; ++kf)
                #pragma unroll
                for (int ni = 0; ni < 2; ++ni) {
                    sa[0][ni] = MFMA16(kreg[ni][kf], aq[0][kf], sa[0][ni]);
                    sa[1][ni] = MFMA16(kreg[ni][kf], aq[1][kf], sa[1][ni]);
                }
            __builtin_amdgcn_s_setprio(0);

            if (i + 1 < nt) loadK(i + 1);   // prefetch: hidden under softmax+PV

            if (lt == p) {                  // only the diagonal tile masks
                #pragma unroll
                for (int qs = 0; qs < 2; ++qs) {
                    const int qg = q0 + 16 * qs + l15;
                    #pragma unroll
                    for (int ni = 0; ni < 2; ++ni)
                        #pragma unroll
                        for (int r = 0; r < 4; ++r)
                            if (kv0 + 16 * ni + 4 * l4 + r > qg) sa[qs][ni][r] = -1e30f;
                }
            }

            // Softmax, base-2, threshold-deferred max (THR=8 -> P <= 256).
            #pragma unroll
            for (int qs = 0; qs < 2; ++qs) {
                float tm = fmaxf(fmaxf(fmaxf(sa[qs][0][0], sa[qs][0][1]),
                                       fmaxf(sa[qs][0][2], sa[qs][0][3])),
                                 fmaxf(fmaxf(sa[qs][1][0], sa[qs][1][1]),
                                       fmaxf(sa[qs][1][2], sa[qs][1][3])));
                if (__any(tm > mx[qs] + 8.0f)) {   // rare: full reduce + rescale
                    tm = fmaxf(tm, __shfl_xor(tm, 16, 64));
                    tm = fmaxf(tm, __shfl_xor(tm, 32, 64));
                    const float mnew = fmaxf(mx[qs], tm);
                    const float c = exp2f(mx[qs] - mnew);
                    f32x4 lt4 = ls_acc[qs];
                    lt4[0] *= c; lt4[1] *= c; lt4[2] *= c; lt4[3] *= c;
                    ls_acc[qs] = lt4;
                    #pragma unroll
                    for (int mf = 0; mf < 8; ++mf) {
                        f32x4 t = o[qs][mf];
                        t[0] *= c; t[1] *= c; t[2] *= c; t[3] *= c;
                        o[qs][mf] = t;
                    }
                    mx[qs] = mnew;
                }
                // P = exp2(S - mx); bounded by 2^8. No sum here (ones-MFMA).
                #pragma unroll
                for (int ni = 0; ni < 2; ++ni) {
                    bf16x4 pv;
                    #pragma unroll
                    for (int r = 0; r < 4; ++r)
                        pv[r] = (bf16_t)exp2f(sa[qs][ni][r] - mx[qs]);
                    *(bf16x4*)(Pw + (16 * qs + l15) * 64
                               + (((2 * ni + (l4 >> 1)) ^ pswz) << 4) + 8 * (l4 & 1)) = pv;
                }
            }

            // V(i) readiness: keep 8 newest (K prefetch), drain stageV(i).
            __builtin_amdgcn_sched_barrier(0);
            asm volatile("s_waitcnt vmcnt(8)" ::: "memory");
            __builtin_amdgcn_sched_barrier(0);

            // O^T += V^T * P^T, plus denominator row: ls += ones * P.
            bf16x8 pa0 = *(const bf16x8*)(Pw + l15 * 64 + ((l4 ^ pswz) << 4));
            bf16x8 pa1 = *(const bf16x8*)(Pw + (16 + l15) * 64 + ((l4 ^ pswz) << 4));
            __builtin_amdgcn_s_setprio(1);
            ls_acc[0] = MFMA16(aones, pa0, ls_acc[0]);
            ls_acc[1] = MFMA16(aones, pa1, ls_acc[1]);
            #pragma unroll
            for (int mf = 0; mf < 8; ++mf) {
                bf16x8 av = *(const bf16x8*)(Vw + (16 * mf + l15) * 64 + ((l4 ^ vswz) << 4));
                o[0][mf] = MFMA16(av, pa0, o[0][mf]);
                o[1][mf] = MFMA16(av, pa1, o[1][mf]);
            }
            __builtin_amdgcn_s_setprio(0);

            if (i + 1 < nt) {
                // WAR guard: V reads retired before overwriting the buffer.
                __builtin_amdgcn_sched_barrier(0);
                asm volatile("s_waitcnt lgkmcnt(0)" ::: "memory");
                __builtin_amdgcn_sched_barrier(0);
                stageV(i + 1);              // lands across the loop-back edge
            }
        }

        // ---- per-atom merge of the 8 kv-split states (two qs-passes) ----
        asm volatile("s_waitcnt vmcnt(0)" ::: "memory");
        #pragma unroll
        for (int qs = 0; qs < 2; ++qs) {
            __syncthreads();    // all waves done with V/P (or prior pass)
            #pragma unroll
            for (int mf = 0; mf < 8; ++mf)
                *(f32x4*)(lds + wid * 8192 + mf * 1024 + lane * 16) = o[qs][mf];
            if (l4 == 0)
                *(float2*)(lds + 65536 + wid * 256 + l15 * 8)
                    = make_float2(mx[qs], ls_acc[qs][0]);
            __syncthreads();
            float mw[8], lw[8];
            #pragma unroll
            for (int w = 0; w < 8; ++w) {
                float2 st = *(const float2*)(lds + 65536 + w * 256 + l15 * 8);
                mw[w] = st.x; lw[w] = st.y;
            }
            float M = mw[0];
            #pragma unroll
            for (int w = 1; w < 8; ++w) M = fmaxf(M, mw[w]);
            float L = 0.f, cw[8];
            #pragma unroll
            for (int w = 0; w < 8; ++w) { cw[w] = exp2f(mw[w] - M); L += lw[w] * cw[w]; }
            const float inv = 1.f / L;
            {
                const int mf = wid;          // this wave's h-slice
                f32x4 acc = (f32x4){0.f, 0.f, 0.f, 0.f};
                #pragma unroll
                for (int w = 0; w < 8; ++w) {
                    f32x4 v = *(const f32x4*)(lds + w * 8192 + mf * 1024 + lane * 16);
                    #pragma unroll
                    for (int e = 0; e < 4; ++e) acc[e] += v[e] * cw[w];
                }
                #pragma unroll
                for (int e = 0; e < 4; ++e) acc[e] *= inv;
                float* op = out + ((size_t)b * 4096 + q0 + 16 * qs + l15) * 128 + 16 * mf + 4 * l4;
                *(f32x4*)op = acc;
            }
        }
        __syncthreads();   // V/P regions safe for next atom
    }
}

extern "C" void kernel_launch(void* const* d_in, const int* in_sizes, int n_in,
                              void* d_out, int out_size, void* d_ws, size_t ws_size,
                              hipStream_t stream) {
    const float* X  = (const float*)d_in[0];
    const float* Wq = (const float*)d_in[1];
    const float* Wk = (const float*)d_in[2];
    const float* Wv = (const float*)d_in[3];
    float* out = (float*)d_out;

    const int M = in_sizes[0] / 1024;      // B*T = 32768
    const int Bn = M / 4096;               // 8

    bf16_t* Qb  = (bf16_t*)d_ws;
    bf16_t* KbP = Qb + (size_t)M * 128;
    bf16_t* VtP = KbP + (size_t)M * 128;   // transposed: [b][128][4096]

    proj_qkv<<<dim3(M / 128, 3), 256, 0, stream>>>(X, Wq, Wk, Wv, Qb, KbP, VtP);
    attn_fwd<<<dim3(64 * Bn), 512, 0, stream>>>(Qb, KbP, VtP, out, Bn);
}

// Round 15
// 230.132 us; speedup vs baseline: 1.5056x; 1.5056x over previous
//
#include <hip/hip_runtime.h>
#include <hip/hip_bf16.h>

typedef __bf16 bf16_t;
typedef __attribute__((ext_vector_type(8))) __bf16 bf16x8;
typedef __attribute__((ext_vector_type(4))) __bf16 bf16x4;
typedef __attribute__((ext_vector_type(4))) float f32x4;

#define MFMA16(a, b, c) __builtin_amdgcn_mfma_f32_16x16x32_bf16((a), (b), (c), 0, 0, 0)

__device__ __forceinline__ void gload_lds16(const void* g, void* l) {
    __builtin_amdgcn_global_load_lds(
        (const __attribute__((address_space(1))) void*)g,
        (__attribute__((address_space(3))) void*)l, 16, 0, 0);
}

// ---------------------------------------------------------------------------
// Kernel 1: QKV projection (unchanged). Q pre-scaled by (1/sqrt(128))*log2e;
// V written transposed as [b][h][t].
// ---------------------------------------------------------------------------
__global__ __launch_bounds__(256, 3) void proj_qkv(
    const float* __restrict__ X,
    const float* __restrict__ W0, const float* __restrict__ W1, const float* __restrict__ W2,
    bf16_t* __restrict__ O0, bf16_t* __restrict__ O1, bf16_t* __restrict__ O2)
{
    __shared__ __align__(16) char As[128 * 128];
    __shared__ __align__(16) char Bs[128 * 128];

    const int tid = threadIdx.x;
    const int wid = tid >> 6;
    const int lane = tid & 63;
    const int l15 = lane & 15, l4 = lane >> 4;
    const int wr = wid >> 1, wc = wid & 1;
    const int m0 = blockIdx.x * 128;

    const float* W = (blockIdx.y == 0) ? W0 : (blockIdx.y == 1 ? W1 : W2);

    const int r0 = tid >> 4;
    const int kq = tid & 15;
    const int swz = ((r0 & 7) << 4);

    f32x4 acc[4][4] = {};
    float4 xr[8];

    #pragma unroll
    for (int i = 0; i < 8; ++i)
        xr[i] = *(const float4*)(X + (size_t)(m0 + r0 + i * 16) * 1024 + kq * 4);

    for (int ks = 0; ks < 16; ++ks) {
        const int kb = ks * 64;
        #pragma unroll
        for (int i = 0; i < 8; ++i) {
            const int r = r0 + i * 16;
            bf16x4 av; av[0] = (bf16_t)xr[i].x; av[1] = (bf16_t)xr[i].y;
            av[2] = (bf16_t)xr[i].z; av[3] = (bf16_t)xr[i].w;
            *(bf16x4*)(As + r * 128 + ((kq * 8) ^ swz)) = av;
        }
        #pragma unroll
        for (int i = 0; i < 8; ++i) {
            const int r = r0 + i * 16;
            float4 wa = *(const float4*)(W + (size_t)r * 1024 + kb + kq * 4);
            bf16x4 wv; wv[0] = (bf16_t)wa.x; wv[1] = (bf16_t)wa.y;
            wv[2] = (bf16_t)wa.z; wv[3] = (bf16_t)wa.w;
            *(bf16x4*)(Bs + r * 128 + ((kq * 8) ^ swz)) = wv;
        }
        __syncthreads();
        if (ks < 15) {
            #pragma unroll
            for (int i = 0; i < 8; ++i)
                xr[i] = *(const float4*)(X + (size_t)(m0 + r0 + i * 16) * 1024 + kb + 64 + kq * 4);
        }
        #pragma unroll
        for (int kk = 0; kk < 64; kk += 32) {
            const int kbyte = 2 * kk + 16 * l4;
            bf16x8 af[4], bfr[4];
            #pragma unroll
            for (int mi = 0; mi < 4; ++mi) {
                int r = wr * 64 + mi * 16 + l15;
                af[mi] = *(const bf16x8*)(As + r * 128 + (kbyte ^ ((r & 7) << 4)));
            }
            #pragma unroll
            for (int ni = 0; ni < 4; ++ni) {
                int r = wc * 64 + ni * 16 + l15;
                bfr[ni] = *(const bf16x8*)(Bs + r * 128 + (kbyte ^ ((r & 7) << 4)));
            }
            #pragma unroll
            for (int mi = 0; mi < 4; ++mi)
                #pragma unroll
                for (int ni = 0; ni < 4; ++ni)
                    acc[mi][ni] = MFMA16(af[mi], bfr[ni], acc[mi][ni]);
        }
        __syncthreads();
    }

    if (blockIdx.y < 2) {
        const float sc = (blockIdx.y == 0) ? 0.12751754816f : 1.0f;  // 1/sqrt(128)*log2e
        bf16_t* O = (blockIdx.y == 0) ? O0 : O1;
        #pragma unroll
        for (int mi = 0; mi < 4; ++mi)
            #pragma unroll
            for (int ni = 0; ni < 4; ++ni) {
                int row = m0 + wr * 64 + mi * 16 + l4 * 4;
                int col = wc * 64 + ni * 16 + l15;
                #pragma unroll
                for (int r = 0; r < 4; ++r)
                    O[(size_t)(row + r) * 128 + col] = (bf16_t)(acc[mi][ni][r] * sc);
            }
    } else {
        #pragma unroll
        for (int mi = 0; mi < 4; ++mi)
            #pragma unroll
            for (int ni = 0; ni < 4; ++ni) {
                int row0 = m0 + wr * 64 + mi * 16 + l4 * 4;
                int col = wc * 64 + ni * 16 + l15;
                int bb = row0 >> 12, t0 = row0 & 4095;
                bf16x4 pk;
                #pragma unroll
                for (int r = 0; r < 4; ++r) pk[r] = (bf16_t)acc[mi][ni][r];
                *(bf16x4*)(O2 + ((size_t)bb << 19) + (size_t)col * 4096 + t0) = pk;
            }
    }
}

// ---------------------------------------------------------------------------
// Kernel 2: causal flash attention — r10/r11 structure with 64-kv tiles.
// 512 blocks x 4 waves (2 blocks/CU), atoms p=j then 127-j; waves kv-split
// mod 4 over 64-kv tiles (65 tiles/block total, equal for all blocks).
// At 2 waves/SIMD the VGPR budget is 256/wave: kreg[4][4] (64 regs) holds a
// full 64-kv K tile, prefetched into the SAME regs (WAR after QK). V via
// global_load_lds (16KB/wave single buffer), counted vmcnt(16); P via
// swizzled per-wave LDS (128B rows, 3-bit XOR key). Base-2 deferred-max
// softmax, ones-MFMA denominator. 68 MFMAs per tile vs 34 before.
// ---------------------------------------------------------------------------
__global__ __launch_bounds__(256, 2) void attn_fwd(
    const bf16_t* __restrict__ Qb, const bf16_t* __restrict__ Kb,
    const bf16_t* __restrict__ Vtg, float* __restrict__ out, int Bn)
{
    // [0,65536): per-wave V buffer (16KB x 4, [128h][128B kv-row], swizzled);
    //            merge reuses as 4 x 8KB O-dump per qs-pass.
    // [65536,81920): per-wave P (4KB x 4); merge stats overlay (P dead).
    __shared__ __align__(16) char lds[81920];

    const int tid = threadIdx.x, wid = tid >> 6, lane = tid & 63;
    const int l15 = lane & 15, l4 = lane >> 4;

    const int blk = blockIdx.x;
    const int b = blk % Bn;              // batch == XCD -> K/V L2-resident
    const int j = blk / Bn;              // 0..63

    const size_t base = (size_t)b * 4096 * 128;
    const size_t baseVT = (size_t)b << 19;

    char* Vw = lds + wid * 16384;
    char* Pw = lds + 65536 + wid * 4096;
    const int key = l15 & 7;             // 3-bit chunk XOR key (row-derived)

    // Constant all-ones A fragment: row-sum MFMA for the softmax denominator.
    bf16x8 aones;
    #pragma unroll
    for (int e = 0; e < 8; ++e) aones[e] = (bf16_t)1.0f;

    for (int seg = 0; seg < 2; ++seg) {
        const int p = seg ? (127 - j) : j;     // 32q atom index
        const int q0 = p << 5;
        const int T = (p >> 1) + 1;            // 64-kv tiles in this atom
        const int nt = (wid < T) ? ((T - 1 - wid) >> 2) + 1 : 0;  // lt = wid+4i

        // Q fragments (B-operand): col q = q0+16qs+l15, k = 32kf+8l4+e.
        bf16x8 aq[2][4];
        #pragma unroll
        for (int qs = 0; qs < 2; ++qs)
            #pragma unroll
            for (int kf = 0; kf < 4; ++kf)
                aq[qs][kf] = *(const bf16x8*)(Qb + base
                    + (size_t)(q0 + 16 * qs + l15) * 128 + 32 * kf + 8 * l4);

        float mx[2] = {-1e30f, -1e30f};
        f32x4 ls_acc[2] = {};              // denominator accumulator (ones-MFMA)
        f32x4 o[2][8] = {};
        bf16x8 kreg[4][4];                 // full 64-kv K tile (64 VGPR)

        // K tile t: rows kv0+16ni+l15, k = 32kf+8l4+e. 16 b128 loads.
        auto loadK = [&](int t) {
            const int kv0 = t << 6;
            const bf16_t* kp = Kb + base + (size_t)(kv0 + l15) * 128 + 8 * l4;
            #pragma unroll
            for (int ni = 0; ni < 4; ++ni)
                #pragma unroll
                for (int kf = 0; kf < 4; ++kf)
                    kreg[ni][kf] = *(const bf16x8*)(kp + (size_t)ni * 2048 + kf * 32);
        };
        // V tile t into Vw: [128h][128B kv-row]; dst linear (gload_lds),
        // source pre-swizzled: phys chunk (lane&7) holds logical (lane&7)^(h&7).
        auto stageV = [&](int t) {
            const int kv0 = t << 6;
            const int hrow = lane >> 3;            // row within 8-row group
            const int lchunk = (lane & 7) ^ (hrow & 7);
            #pragma unroll
            for (int c = 0; c < 16; ++c) {
                const bf16_t* src = Vtg + baseVT + (size_t)(8 * c + hrow) * 4096
                                    + kv0 + lchunk * 8;
                gload_lds16(src, Vw + c * 1024);
            }
        };

        if (nt > 0) { loadK(wid); stageV(wid); }

        for (int i = 0; i < nt; ++i) {
            const int lt = wid + 4 * i;
            const int kv0 = lt << 6;
            const int ltn = (i + 1 < nt) ? lt + 4 : lt;   // clamp keeps vmcnt exact

            // S^T = K * Q^T : D row = kv (16ni+4l4+r), col = q (l15).
            f32x4 sa[2][4];
            #pragma unroll
            for (int qs = 0; qs < 2; ++qs)
                #pragma unroll
                for (int ni = 0; ni < 4; ++ni) sa[qs][ni] = (f32x4){0.f, 0.f, 0.f, 0.f};
            __builtin_amdgcn_s_setprio(1);
            #pragma unroll
            for (int kf = 0; kf < 4; ++kf)
                #pragma unroll
                for (int ni = 0; ni < 4; ++ni) {
                    sa[0][ni] = MFMA16(kreg[ni][kf], aq[0][kf], sa[0][ni]);
                    sa[1][ni] = MFMA16(kreg[ni][kf], aq[1][kf], sa[1][ni]);
                }
            __builtin_amdgcn_s_setprio(0);

            loadK(ltn);                     // prefetch into same regs (WAR ok)

            if (lt == T - 1) {              // only the last tile masks
                #pragma unroll
                for (int qs = 0; qs < 2; ++qs) {
                    const int qg = q0 + 16 * qs + l15;
                    #pragma unroll
                    for (int ni = 0; ni < 4; ++ni)
                        #pragma unroll
                        for (int r = 0; r < 4; ++r)
                            if (kv0 + 16 * ni + 4 * l4 + r > qg) sa[qs][ni][r] = -1e30f;
                }
            }

            // Softmax, base-2, threshold-deferred max (THR=8 -> P <= 256).
            #pragma unroll
            for (int qs = 0; qs < 2; ++qs) {
                float tm = -1e30f;
                #pragma unroll
                for (int ni = 0; ni < 4; ++ni)
                    tm = fmaxf(tm, fmaxf(fmaxf(sa[qs][ni][0], sa[qs][ni][1]),
                                         fmaxf(sa[qs][ni][2], sa[qs][ni][3])));
                if (__any(tm > mx[qs] + 8.0f)) {   // rare: full reduce + rescale
                    tm = fmaxf(tm, __shfl_xor(tm, 16, 64));
                    tm = fmaxf(tm, __shfl_xor(tm, 32, 64));
                    const float mnew = fmaxf(mx[qs], tm);
                    const float c = exp2f(mx[qs] - mnew);
                    f32x4 lt4 = ls_acc[qs];
                    lt4[0] *= c; lt4[1] *= c; lt4[2] *= c; lt4[3] *= c;
                    ls_acc[qs] = lt4;
                    #pragma unroll
                    for (int mf = 0; mf < 8; ++mf) {
                        f32x4 t = o[qs][mf];
                        t[0] *= c; t[1] *= c; t[2] *= c; t[3] *= c;
                        o[qs][mf] = t;
                    }
                    mx[qs] = mnew;
                }
                // P = exp2(S - mx); row 16qs+l15 (128B), logical chunk
                // x = 2ni+(l4>>1), phys = x ^ key, byte 8*(l4&1).
                #pragma unroll
                for (int ni = 0; ni < 4; ++ni) {
                    bf16x4 pv;
                    #pragma unroll
                    for (int r = 0; r < 4; ++r)
                        pv[r] = (bf16_t)exp2f(sa[qs][ni][r] - mx[qs]);
                    *(bf16x4*)(Pw + (16 * qs + l15) * 128
                               + (((2 * ni + (l4 >> 1)) ^ key) << 4) + 8 * (l4 & 1)) = pv;
                }
            }

            // V(lt) readiness: keep 16 newest (loadK(ltn)), drain stageV(lt).
            __builtin_amdgcn_sched_barrier(0);
            asm volatile("s_waitcnt vmcnt(16)" ::: "memory");
            __builtin_amdgcn_sched_barrier(0);

            // O^T += V^T * P^T over K=64 (two kfp halves) + ones-MFMA denom.
            __builtin_amdgcn_s_setprio(1);
            #pragma unroll
            for (int kfp = 0; kfp < 2; ++kfp) {
                const int cb = ((4 * kfp + l4) ^ key) << 4;
                bf16x8 pa0 = *(const bf16x8*)(Pw + l15 * 128 + cb);
                bf16x8 pa1 = *(const bf16x8*)(Pw + (16 + l15) * 128 + cb);
                ls_acc[0] = MFMA16(aones, pa0, ls_acc[0]);
                ls_acc[1] = MFMA16(aones, pa1, ls_acc[1]);
                #pragma unroll
                for (int mf = 0; mf < 8; ++mf) {
                    bf16x8 av = *(const bf16x8*)(Vw + (16 * mf + l15) * 128 + cb);
                    o[0][mf] = MFMA16(av, pa0, o[0][mf]);
                    o[1][mf] = MFMA16(av, pa1, o[1][mf]);
                }
            }
            __builtin_amdgcn_s_setprio(0);

            // WAR guard: V reads retired before re-staging the buffer.
            __builtin_amdgcn_sched_barrier(0);
            asm volatile("s_waitcnt lgkmcnt(0)" ::: "memory");
            __builtin_amdgcn_sched_barrier(0);
            stageV(ltn);                    // lands across the loop-back edge
        }

        // ---- per-atom merge of the 4 kv-split states (two qs-passes) ----
        asm volatile("s_waitcnt vmcnt(0)" ::: "memory");
        #pragma unroll
        for (int qs = 0; qs < 2; ++qs) {
            __syncthreads();    // all waves done with V/P (or prior pass)
            #pragma unroll
            for (int mf = 0; mf < 8; ++mf)
                *(f32x4*)(lds + wid * 8192 + mf * 1024 + lane * 16) = o[qs][mf];
            if (l4 == 0)
                *(float2*)(lds + 65536 + wid * 256 + l15 * 8)
                    = make_float2(mx[qs], ls_acc[qs][0]);
            __syncthreads();
            float mw[4], lw[4];
            #pragma unroll
            for (int w = 0; w < 4; ++w) {
                float2 st = *(const float2*)(lds + 65536 + w * 256 + l15 * 8);
                mw[w] = st.x; lw[w] = st.y;
            }
            const float M = fmaxf(fmaxf(mw[0], mw[1]), fmaxf(mw[2], mw[3]));
            float cw[4], L = 0.f;
            #pragma unroll
            for (int w = 0; w < 4; ++w) { cw[w] = exp2f(mw[w] - M); L += lw[w] * cw[w]; }
            const float inv = 1.f / L;
            #pragma unroll
            for (int mm = 0; mm < 2; ++mm) {
                const int mf = 2 * wid + mm;    // this wave's h-slice
                f32x4 acc = (f32x4){0.f, 0.f, 0.f, 0.f};
                #pragma unroll
                for (int w = 0; w < 4; ++w) {
                    f32x4 v = *(const f32x4*)(lds + w * 8192 + mf * 1024 + lane * 16);
                    #pragma unroll
                    for (int e = 0; e < 4; ++e) acc[e] += v[e] * cw[w];
                }
                #pragma unroll
                for (int e = 0; e < 4; ++e) acc[e] *= inv;
                float* op = out + ((size_t)b * 4096 + q0 + 16 * qs + l15) * 128 + 16 * mf + 4 * l4;
                *(f32x4*)op = acc;
            }
        }
        __syncthreads();   // V/P regions safe for next atom
    }
}

extern "C" void kernel_launch(void* const* d_in, const int* in_sizes, int n_in,
                              void* d_out, int out_size, void* d_ws, size_t ws_size,
                              hipStream_t stream) {
    const float* X  = (const float*)d_in[0];
    const float* Wq = (const float*)d_in[1];
    const float* Wk = (const float*)d_in[2];
    const float* Wv = (const float*)d_in[3];
    float* out = (float*)d_out;

    const int M = in_sizes[0] / 1024;      // B*T = 32768
    const int Bn = M / 4096;               // 8

    bf16_t* Qb  = (bf16_t*)d_ws;
    bf16_t* KbP = Qb + (size_t)M * 128;
    bf16_t* VtP = KbP + (size_t)M * 128;   // transposed: [b][128][4096]

    proj_qkv<<<dim3(M / 128, 3), 256, 0, stream>>>(X, Wq, Wk, Wv, Qb, KbP, VtP);
    attn_fwd<<<dim3(64 * Bn), 256, 0, stream>>>(Qb, KbP, VtP, out, Bn);
}

// Round 16
// 125.574 us; speedup vs baseline: 2.7593x; 1.8326x over previous
//
#include <hip/hip_runtime.h>
#include <hip/hip_bf16.h>

typedef __bf16 bf16_t;
typedef __attribute__((ext_vector_type(8))) __bf16 bf16x8;
typedef __attribute__((ext_vector_type(4))) __bf16 bf16x4;
typedef __attribute__((ext_vector_type(4))) float f32x4;

#define MFMA16(a, b, c) __builtin_amdgcn_mfma_f32_16x16x32_bf16((a), (b), (c), 0, 0, 0)

__device__ __forceinline__ void gload_lds16(const void* g, void* l) {
    __builtin_amdgcn_global_load_lds(
        (const __attribute__((address_space(1))) void*)g,
        (__attribute__((address_space(3))) void*)l, 16, 0, 0);
}

// ---------------------------------------------------------------------------
// Kernel 1: QKV projection (unchanged). Q pre-scaled by (1/sqrt(128))*log2e;
// V written transposed as [b][h][t].
// ---------------------------------------------------------------------------
__global__ __launch_bounds__(256, 3) void proj_qkv(
    const float* __restrict__ X,
    const float* __restrict__ W0, const float* __restrict__ W1, const float* __restrict__ W2,
    bf16_t* __restrict__ O0, bf16_t* __restrict__ O1, bf16_t* __restrict__ O2)
{
    __shared__ __align__(16) char As[128 * 128];
    __shared__ __align__(16) char Bs[128 * 128];

    const int tid = threadIdx.x;
    const int wid = tid >> 6;
    const int lane = tid & 63;
    const int l15 = lane & 15, l4 = lane >> 4;
    const int wr = wid >> 1, wc = wid & 1;
    const int m0 = blockIdx.x * 128;

    const float* W = (blockIdx.y == 0) ? W0 : (blockIdx.y == 1 ? W1 : W2);

    const int r0 = tid >> 4;
    const int kq = tid & 15;
    const int swz = ((r0 & 7) << 4);

    f32x4 acc[4][4] = {};
    float4 xr[8];

    #pragma unroll
    for (int i = 0; i < 8; ++i)
        xr[i] = *(const float4*)(X + (size_t)(m0 + r0 + i * 16) * 1024 + kq * 4);

    for (int ks = 0; ks < 16; ++ks) {
        const int kb = ks * 64;
        #pragma unroll
        for (int i = 0; i < 8; ++i) {
            const int r = r0 + i * 16;
            bf16x4 av; av[0] = (bf16_t)xr[i].x; av[1] = (bf16_t)xr[i].y;
            av[2] = (bf16_t)xr[i].z; av[3] = (bf16_t)xr[i].w;
            *(bf16x4*)(As + r * 128 + ((kq * 8) ^ swz)) = av;
        }
        #pragma unroll
        for (int i = 0; i < 8; ++i) {
            const int r = r0 + i * 16;
            float4 wa = *(const float4*)(W + (size_t)r * 1024 + kb + kq * 4);
            bf16x4 wv; wv[0] = (bf16_t)wa.x; wv[1] = (bf16_t)wa.y;
            wv[2] = (bf16_t)wa.z; wv[3] = (bf16_t)wa.w;
            *(bf16x4*)(Bs + r * 128 + ((kq * 8) ^ swz)) = wv;
        }
        __syncthreads();
        if (ks < 15) {
            #pragma unroll
            for (int i = 0; i < 8; ++i)
                xr[i] = *(const float4*)(X + (size_t)(m0 + r0 + i * 16) * 1024 + kb + 64 + kq * 4);
        }
        #pragma unroll
        for (int kk = 0; kk < 64; kk += 32) {
            const int kbyte = 2 * kk + 16 * l4;
            bf16x8 af[4], bfr[4];
            #pragma unroll
            for (int mi = 0; mi < 4; ++mi) {
                int r = wr * 64 + mi * 16 + l15;
                af[mi] = *(const bf16x8*)(As + r * 128 + (kbyte ^ ((r & 7) << 4)));
            }
            #pragma unroll
            for (int ni = 0; ni < 4; ++ni) {
                int r = wc * 64 + ni * 16 + l15;
                bfr[ni] = *(const bf16x8*)(Bs + r * 128 + (kbyte ^ ((r & 7) << 4)));
            }
            #pragma unroll
            for (int mi = 0; mi < 4; ++mi)
                #pragma unroll
                for (int ni = 0; ni < 4; ++ni)
                    acc[mi][ni] = MFMA16(af[mi], bfr[ni], acc[mi][ni]);
        }
        __syncthreads();
    }

    if (blockIdx.y < 2) {
        const float sc = (blockIdx.y == 0) ? 0.12751754816f : 1.0f;  // 1/sqrt(128)*log2e
        bf16_t* O = (blockIdx.y == 0) ? O0 : O1;
        #pragma unroll
        for (int mi = 0; mi < 4; ++mi)
            #pragma unroll
            for (int ni = 0; ni < 4; ++ni) {
                int row = m0 + wr * 64 + mi * 16 + l4 * 4;
                int col = wc * 64 + ni * 16 + l15;
                #pragma unroll
                for (int r = 0; r < 4; ++r)
                    O[(size_t)(row + r) * 128 + col] = (bf16_t)(acc[mi][ni][r] * sc);
            }
    } else {
        #pragma unroll
        for (int mi = 0; mi < 4; ++mi)
            #pragma unroll
            for (int ni = 0; ni < 4; ++ni) {
                int row0 = m0 + wr * 64 + mi * 16 + l4 * 4;
                int col = wc * 64 + ni * 16 + l15;
                int bb = row0 >> 12, t0 = row0 & 4095;
                bf16x4 pk;
                #pragma unroll
                for (int r = 0; r < 4; ++r) pk[r] = (bf16_t)acc[mi][ni][r];
                *(bf16x4*)(O2 + ((size_t)bb << 19) + (size_t)col * 4096 + t0) = pk;
            }
    }
}

// ---------------------------------------------------------------------------
// Kernel 2: causal flash attention — r2 architecture + equal-length atoms.
// 512 blocks x 4 waves (2 blocks/CU). Block: atoms p=j then 127-j, 32 q each.
// Waves = (pair, qh): pair splits 64-kv tiles even/odd; qh splits the 32 q
// into 2x16. K tile [64kv][128k] + V^T tile [128h][64kv] staged to LDS per
// pair via global_load_lds with pre-swizzled sources (conflict-free reads);
// exactly 33 barrier-synced steps per block regardless of j. Swapped QK^T
// (S^T = K*Q^T) keeps softmax lane-local per q; base-2 + deferred max +
// ones-MFMA denominator. One 2-way kv-merge per atom. Light registers:
// o=32acc, sa=16acc, aq=16arch -> no spill possible.
// ---------------------------------------------------------------------------
__global__ __launch_bounds__(256, 2) void attn_fwd(
    const bf16_t* __restrict__ Qb, const bf16_t* __restrict__ Kb,
    const bf16_t* __restrict__ Vtg, float* __restrict__ out, int Bn)
{
    // [0,65536): Ks[pair] 16KB @ pair*32768; Vt[pair] 16KB @ +16384.
    //            merge reuse: o-dump 2x8KB @ qh*8192; stats @ 49152.
    // [65536,73728): per-wave P (2KB each: [16 q][128B kv-row]).
    __shared__ __align__(16) char lds[73728];

    const int tid = threadIdx.x, wid = tid >> 6, lane = tid & 63;
    const int l15 = lane & 15, l4 = lane >> 4;
    const int pair = wid >> 1, qh = wid & 1;

    const int blk = blockIdx.x;
    const int b = blk % Bn;              // batch == XCD -> K/V L2-resident
    const int j = blk / Bn;              // 0..63

    const size_t base = (size_t)b * 4096 * 128;
    const size_t baseVT = (size_t)b << 19;

    char* Kbuf = lds + pair * 32768;
    char* Vbuf = Kbuf + 16384;
    char* Pw   = lds + 65536 + wid * 2048;
    const int key = l15 & 7;             // 3-bit 16B-chunk XOR key

    bf16x8 aones;
    #pragma unroll
    for (int e = 0; e < 8; ++e) aones[e] = (bf16_t)1.0f;

    for (int seg = 0; seg < 2; ++seg) {
        const int p = seg ? (127 - j) : j;     // 32q atom
        const int q0 = p << 5;
        const int T = (p >> 1) + 1;            // 64-kv tiles in atom
        const int smax = (T + 1) >> 1;         // pair-0 step count (>= pair-1)
        const int qg = q0 + 16 * qh + l15;     // this lane's q row

        // Q fragment (B-operand): col q = qg, k = 32kf+8l4+e. Pre-scaled.
        bf16x8 aq[4];
        #pragma unroll
        for (int kf = 0; kf < 4; ++kf)
            aq[kf] = *(const bf16x8*)(Qb + base + (size_t)qg * 128 + 32 * kf + 8 * l4);

        float mx = -1e30f;
        f32x4 ls_acc = (f32x4){0.f, 0.f, 0.f, 0.f};
        f32x4 o[8] = {};

        // Stage this pair's tile for step s. qh=0 wave: K; qh=1 wave: V^T.
        auto stage = [&](int s) {
            const int lt = 2 * s + pair;
            if (lt >= T) return;
            const int kv0 = lt << 6;
            if (qh == 0) {
                // K: [64 kv][256B rows]; LDS linear, source pre-swizzled.
                #pragma unroll
                for (int it = 0; it < 16; ++it) {
                    const int row = it * 4 + (lane >> 4);
                    const bf16_t* src = Kb + base + (size_t)(kv0 + row) * 128
                                        + (((lane & 15) ^ (row & 7)) << 3);
                    gload_lds16(src, Kbuf + it * 1024);
                }
            } else {
                // V^T: [128 h][128B rows].
                #pragma unroll
                for (int it = 0; it < 16; ++it) {
                    const int h = it * 8 + (lane >> 3);
                    const bf16_t* src = Vtg + baseVT + (size_t)h * 4096 + kv0
                                        + (((lane & 7) ^ ((lane >> 3) & 7)) << 3);
                    gload_lds16(src, Vbuf + it * 1024);
                }
            }
        };

        __syncthreads();          // previous merge reads complete
        stage(0);
        __syncthreads();          // tile 0 visible (vmcnt drained at barrier)

        for (int s = 0; s < smax; ++s) {
            const int lt = 2 * s + pair;
            if (lt < T) {
                const int kv0 = lt << 6;

                // S^T = K * Q^T : D row = kv (16ni+4l4+r), col = q (l15).
                f32x4 sa[4];
                #pragma unroll
                for (int ni = 0; ni < 4; ++ni) sa[ni] = (f32x4){0.f, 0.f, 0.f, 0.f};
                __builtin_amdgcn_s_setprio(1);
                #pragma unroll
                for (int kf = 0; kf < 4; ++kf)
                    #pragma unroll
                    for (int ni = 0; ni < 4; ++ni) {
                        bf16x8 ak = *(const bf16x8*)(Kbuf + (16 * ni + l15) * 256
                                                     + (((4 * kf + l4) ^ key) << 4));
                        sa[ni] = MFMA16(ak, aq[kf], sa[ni]);
                    }
                __builtin_amdgcn_s_setprio(0);

                if (lt == T - 1) {          // only the diagonal tile masks
                    #pragma unroll
                    for (int ni = 0; ni < 4; ++ni)
                        #pragma unroll
                        for (int r = 0; r < 4; ++r)
                            if (kv0 + 16 * ni + 4 * l4 + r > qg) sa[ni][r] = -1e30f;
                }

                // Softmax, base-2, threshold-deferred max (THR=8 -> P <= 256).
                float tm = -1e30f;
                #pragma unroll
                for (int ni = 0; ni < 4; ++ni)
                    tm = fmaxf(tm, fmaxf(fmaxf(sa[ni][0], sa[ni][1]),
                                         fmaxf(sa[ni][2], sa[ni][3])));
                if (__any(tm > mx + 8.0f)) {   // rare: full reduce + rescale
                    tm = fmaxf(tm, __shfl_xor(tm, 16, 64));
                    tm = fmaxf(tm, __shfl_xor(tm, 32, 64));
                    const float mnew = fmaxf(mx, tm);
                    const float c = exp2f(mx - mnew);
                    ls_acc[0] *= c; ls_acc[1] *= c; ls_acc[2] *= c; ls_acc[3] *= c;
                    #pragma unroll
                    for (int mf = 0; mf < 8; ++mf) {
                        f32x4 t = o[mf];
                        t[0] *= c; t[1] *= c; t[2] *= c; t[3] *= c;
                        o[mf] = t;
                    }
                    mx = mnew;
                }
                // P write: row q-in-wave = l15 (128B rows), swizzled b64.
                #pragma unroll
                for (int ni = 0; ni < 4; ++ni) {
                    bf16x4 pv;
                    #pragma unroll
                    for (int r = 0; r < 4; ++r)
                        pv[r] = (bf16_t)exp2f(sa[ni][r] - mx);
                    *(bf16x4*)(Pw + l15 * 128
                               + (((2 * ni + (l4 >> 1)) ^ key) << 4) + 8 * (l4 & 1)) = pv;
                }

                // O^T += V^T * P^T (+ ones-MFMA denominator).
                __builtin_amdgcn_s_setprio(1);
                #pragma unroll
                for (int kfp = 0; kfp < 2; ++kfp) {
                    const int cb = ((4 * kfp + l4) ^ key) << 4;
                    bf16x8 pb = *(const bf16x8*)(Pw + l15 * 128 + cb);
                    ls_acc = MFMA16(aones, pb, ls_acc);
                    #pragma unroll
                    for (int mf = 0; mf < 8; ++mf) {
                        bf16x8 av = *(const bf16x8*)(Vbuf + (16 * mf + l15) * 128 + cb);
                        o[mf] = MFMA16(av, pb, o[mf]);
                    }
                }
                __builtin_amdgcn_s_setprio(0);
            }
            if (s + 1 < smax) {
                __syncthreads();   // all waves done reading current tiles
                stage(s + 1);
                __syncthreads();   // staged data visible
            }
        }

        // ---- 2-way kv-merge (pair 1 -> pair 0), then store ----
        __syncthreads();
        if (pair == 1) {
            char* dst = lds + qh * 8192;
            #pragma unroll
            for (int mf = 0; mf < 8; ++mf)
                *(f32x4*)(dst + mf * 1024 + lane * 16) = o[mf];
            *(float2*)(lds + 49152 + qh * 512 + lane * 8) = make_float2(mx, ls_acc[0]);
        }
        __syncthreads();
        if (pair == 0) {
            float2 st = *(const float2*)(lds + 49152 + qh * 512 + lane * 8);
            const float mB = st.x, lB = st.y;
            const float M = fmaxf(mx, mB);
            const float a = exp2f(mx - M), b2 = exp2f(mB - M);
            const float linv = 1.f / (ls_acc[0] * a + lB * b2);
            char* srcO = lds + qh * 8192;
            float* op = out + ((size_t)b * 4096 + qg) * 128 + 4 * l4;
            #pragma unroll
            for (int mf = 0; mf < 8; ++mf) {
                f32x4 ob = *(const f32x4*)(srcO + mf * 1024 + lane * 16);
                f32x4 r;
                #pragma unroll
                for (int e = 0; e < 4; ++e) r[e] = (o[mf][e] * a + ob[e] * b2) * linv;
                *(f32x4*)(op + 16 * mf) = r;
            }
        }
    }
}

extern "C" void kernel_launch(void* const* d_in, const int* in_sizes, int n_in,
                              void* d_out, int out_size, void* d_ws, size_t ws_size,
                              hipStream_t stream) {
    const float* X  = (const float*)d_in[0];
    const float* Wq = (const float*)d_in[1];
    const float* Wk = (const float*)d_in[2];
    const float* Wv = (const float*)d_in[3];
    float* out = (float*)d_out;

    const int M = in_sizes[0] / 1024;      // B*T = 32768
    const int Bn = M / 4096;               // 8

    bf16_t* Qb  = (bf16_t*)d_ws;
    bf16_t* KbP = Qb + (size_t)M * 128;
    bf16_t* VtP = KbP + (size_t)M * 128;   // transposed: [b][128][4096]

    proj_qkv<<<dim3(M / 128, 3), 256, 0, stream>>>(X, Wq, Wk, Wv, Qb, KbP, VtP);
    attn_fwd<<<dim3(64 * Bn), 256, 0, stream>>>(Qb, KbP, VtP, out, Bn);
}